// Round 11
// baseline (434.974 us; speedup 1.0000x reference)
//
#include <hip/hip_runtime.h>
#include <hip/hip_bf16.h>

// Correlation, MAX_DISP=4, bf16 MFMA Gram tiles. R11 = R10 formulas + TH=2.
// out[b, dx*9+dy, h, w] = mean_c x1[b,c,h,w]*x2[b,c,h+dx-4,w+dy-4]
// x1,x2: (8,64,256,256) fp32. out: (8,81,256,256) fp32.
//
// WG = (b, h-pair, w-quarter). 512 thr = 8 waves; wave = (hl, pt):
// hl = output row h0+hl, pt = 16-wide p-tile. Per dx: x2 row hl+dx of the
// 10 staged rows; 2 q-tiles (offsets -4, +12). dy = n-m / n-m+16 (m89 C/D).
// LDS k-major packed k-pairs (m97-verified fragment layout), strides 68/84
// dw -> 2-way bank alias (free). x2 staging: chunk-2 load/write split to
// break the per-item load->cvt->ds_write serial chain (R10's main stall).

namespace {
constexpr int kC  = 64;
constexpr int kH  = 256;
constexpr int kW  = 256;
constexpr int kHW = kH * kW;
constexpr int kD  = 9;
constexpr int kX1Str  = 68;                   // dw per kpair row (x1)
constexpr int kX1Blk  = 16 * kX1Str;          // 1088 dw per hl
constexpr int kX2Str  = 84;                   // dw per kpair row (x2)
constexpr int kX2Blk  = 16 * kX2Str;          // 1344 dw per x2 source row
constexpr int kX2Base = 2 * kX1Blk;           // 2176
constexpr int kLdsDw  = kX2Base + 10 * kX2Blk;  // 15616 dw = 62464 B
}  // namespace

using short8 = __attribute__((ext_vector_type(8))) short;
using f32x4  = __attribute__((ext_vector_type(4))) float;

__device__ __forceinline__ unsigned pkbf(float lo, float hi) {
  const unsigned short a =
      __builtin_bit_cast(unsigned short, __float2bfloat16(lo));
  const unsigned short b =
      __builtin_bit_cast(unsigned short, __float2bfloat16(hi));
  return (unsigned)a | ((unsigned)b << 16);
}

__global__ __launch_bounds__(512) void corr_mfma(
    const float* __restrict__ x1, const float* __restrict__ x2,
    float* __restrict__ out) {
  __shared__ __attribute__((aligned(16))) unsigned lds[kLdsDw];
  float* ldsf = (float*)lds;  // epilogue alias (2*81*68 = 11016 dw < kLdsDw)

  const int b    = blockIdx.x & 7;   // batch -> XCD (round-robin dispatch)
  const int slot = blockIdx.x >> 3;
  const int hp   = slot >> 2;        // 0..127
  const int wq   = slot & 3;
  const int h0   = 2 * hp;
  const int w0   = wq * 64;

  const int tid  = (int)threadIdx.x;
  const int wv   = tid >> 6;   // 0..7
  const int hl   = wv >> 2;    // output row h0+hl
  const int pt   = wv & 3;     // p-tile
  const int lane = tid & 63;
  const int lg   = lane >> 4;  // k-group
  const int ln   = lane & 15;  // row/col within tile

  f32x4 acc[kD][2];
#pragma unroll
  for (int dx = 0; dx < kD; ++dx)
#pragma unroll
    for (int qt = 0; qt < 2; ++qt) acc[dx][qt] = (f32x4)0.0f;

  // x1 staging role (1 item/thread): (hl_s, kpair, w-quad)
  const int hs1 = tid >> 8, kp1 = (tid >> 4) & 15, q1 = tid & 15;
  const float4 z4 = make_float4(0.f, 0.f, 0.f, 0.f);

#pragma unroll 1
  for (int pass = 0; pass < 2; ++pass) {
    const int c0 = pass * 32;

    // ---- stage x1: 2 hl x 16 kpair x 16 quads ----
    {
      const float* s1 = x1 + ((size_t)(b * kC + c0 + 2 * kp1) * kH +
                              (h0 + hs1)) * kW + w0 + 4 * q1;
      const float4 v0 = *(const float4*)s1;
      const float4 v1 = *(const float4*)(s1 + kHW);
      uint4 q;
      q.x = pkbf(v0.x, v1.x); q.y = pkbf(v0.y, v1.y);
      q.z = pkbf(v0.z, v1.z); q.w = pkbf(v0.w, v1.w);
      *(uint4*)&lds[hs1 * kX1Blk + kp1 * kX1Str + 4 * q1] = q;
    }

    // ---- stage x2: 10 r x 16 kpair x 20 quads (cols w0-4..w0+75) ----
    // chunk-2: issue both items' loads, then both converts+writes.
#pragma unroll 1
    for (int i0 = 0; i0 < 8; i0 += 2) {
      float4 v0[2], v1[2];
      int dst[2];
      bool ok[2];
#pragma unroll
      for (int j = 0; j < 2; ++j) {
        const int s = tid + 512 * (i0 + j);
        ok[j] = (s < 3200);
        const int q20 = s % 20;
        const int kp  = (s / 20) & 15;
        const int r   = s / 320;
        const int g   = h0 + r - 4;
        const int w   = w0 - 4 + 4 * q20;
        const bool ld = ok[j] && g >= 0 && g < kH && w >= 0 && w <= kW - 4;
        const float* s2 = x2 + ((size_t)(b * kC + c0 + 2 * kp) * kH +
                                (size_t)(ld ? g : 0)) * kW + (ld ? w : 0);
        v0[j] = ld ? *(const float4*)s2 : z4;
        v1[j] = ld ? *(const float4*)(s2 + kHW) : z4;
        dst[j] = kX2Base + r * kX2Blk + kp * kX2Str + 4 * q20;
      }
#pragma unroll
      for (int j = 0; j < 2; ++j) {
        if (ok[j]) {
          uint4 q;
          q.x = pkbf(v0[j].x, v1[j].x); q.y = pkbf(v0[j].y, v1[j].y);
          q.z = pkbf(v0[j].z, v1[j].z); q.w = pkbf(v0[j].w, v1[j].w);
          *(uint4*)&lds[dst[j]] = q;
        }
      }
    }
    __syncthreads();

    // ---- compute: A once, then 9 dx x 2 q-tiles ----
    union Frag { unsigned u[4]; short8 s; };
    Frag fa;
#pragma unroll
    for (int r = 0; r < 4; ++r)
      fa.u[r] = lds[hl * kX1Blk + (lg * 4 + r) * kX1Str + pt * 16 + ln];

#pragma unroll
    for (int dx = 0; dx < kD; ++dx) {
      const int rb = kX2Base + (hl + dx) * kX2Blk;
#pragma unroll
      for (int qt = 0; qt < 2; ++qt) {
        const int qb = pt * 16 + qt * 16 + ln;  // staged col 0..79
        Frag fb;
#pragma unroll
        for (int r = 0; r < 4; ++r)
          fb.u[r] = lds[rb + (lg * 4 + r) * kX2Str + qb];
        acc[dx][qt] = __builtin_amdgcn_mfma_f32_16x16x32_bf16(
            fa.s, fb.s, acc[dx][qt], 0, 0, 0);
      }
    }
    __syncthreads();
  }

  // ---- epilogue: diagonal extract via LDS, then coalesced store ----
  // D[m][n]: m = lg*4+reg (p), n = ln (q). left: dy = n-m; right: +16.
  const float inv = 1.0f / 64.0f;
#pragma unroll
  for (int dx = 0; dx < kD; ++dx)
#pragma unroll
    for (int r = 0; r < 4; ++r) {
      const int m = lg * 4 + r;
      const int dyL = ln - m;
      if (dyL >= 0 && dyL <= 8)
        ldsf[(hl * 81 + dx * 9 + dyL) * 68 + pt * 16 + m] = acc[dx][0][r] * inv;
      const int dyR = ln - m + 16;
      if (dyR <= 8)
        ldsf[(hl * 81 + dx * 9 + dyR) * 68 + pt * 16 + m] = acc[dx][1][r] * inv;
    }
  __syncthreads();

#pragma unroll
  for (int i = 0; i < 6; ++i) {
    const int s = tid + 512 * i;
    if (s < 2592) {  // 2 hl x 81 d x 16 quads
      const int hs = s / 1296;
      const int rem = s - hs * 1296;
      const int dd = rem >> 4, q = rem & 15;
      const float4 v = *(const float4*)&ldsf[(hs * 81 + dd) * 68 + 4 * q];
      *(float4*)(out + (((size_t)b * 81 + dd) * kH + h0 + hs) * kW + w0 +
                 4 * q) = v;
    }
  }
}

extern "C" void kernel_launch(void* const* d_in, const int* in_sizes, int n_in,
                              void* d_out, int out_size, void* d_ws, size_t ws_size,
                              hipStream_t stream) {
  const float* x1 = (const float*)d_in[0];
  const float* x2 = (const float*)d_in[1];
  float* out = (float*)d_out;
  const int grid = 8 * (kH / 2) * 4;  // (b, h-pair, w-quarter) = 4096 WGs
  corr_mfma<<<grid, 512, 0, stream>>>(x1, x2, out);
}